// Round 7
// baseline (108.949 us; speedup 1.0000x reference)
//
#include <hip/hip_runtime.h>
#include <hip/hip_bf16.h>

// Flash-attention fwd, fp32 in/out, bf16 MFMA compute.
// B=64 (batch*heads), L=1024, D=64. scale = 1/sqrt(512). mask==true -> -1e9.
// R7: swapped QK^T (mfma(K,Q)) -> per-lane softmax rows; LDS-op count cut
//     ~106 -> ~46 per thread-tile (mask 4xb32, P 4xb64, V-stage 4xb64 via
//     register 4x4 transpose, shuffles 32 -> 8). Register-prefetch kept.

typedef __attribute__((ext_vector_type(4))) float f32x4;
typedef __attribute__((ext_vector_type(8))) short bf16x8;
typedef __attribute__((ext_vector_type(4))) short short4v;

constexpr int B_ = 64;
constexpr int L_ = 1024;
constexpr int D_ = 64;
constexpr int QBLK = 64;     // q rows per block (4 waves x 16)
constexpr int KV = 64;       // keys per tile
constexpr int NKV = L_ / KV; // 16 tiles
constexpr int STR = 72;      // shorts per LDS row (64 + 8 pad)
constexpr int STRB = 72;     // mask bytes per row
constexpr float INV_TEMP = 0.04419417382415922f; // 1/sqrt(512)
constexpr float NEG = -1e9f;

__device__ inline short f2bf(float f) {
  __hip_bfloat16 h = __float2bfloat16(f);
  short s; __builtin_memcpy(&s, &h, 2);
  return s;
}

__global__ __launch_bounds__(256) void attn_fwd(
    const float* __restrict__ Q, const float* __restrict__ K,
    const float* __restrict__ V, const int* __restrict__ M,
    float* __restrict__ O)
{
  __shared__ short k_lds[KV][STR];            // K tile, [key][d]
  __shared__ short vt_lds[D_][STR];           // V tile transposed, [d][key]
  __shared__ short p_lds[4][16][STR];         // per-wave P, [qrow(c)][key]
  __shared__ unsigned char m_lds[QBLK][STRB]; // mask tile, 1B/elem [qrow][key]

  const int qt   = blockIdx.x;
  const int b    = blockIdx.y;
  const int tid  = threadIdx.x;
  const int w    = tid >> 6;
  const int lane = tid & 63;
  const int g    = lane >> 4; // 16-lane group 0..3
  const int c    = lane & 15;

  const int q0 = qt * QBLK;

  // ---- Q fragment (B operand of swapped QK^T): col=c -> q-row w*16+c,
  //      k-elem = ks*32 + g*8 + j over d. Same data layout as before.
  bf16x8 qf[2];
  {
    const float* qp = Q + ((size_t)b * L_ + q0 + w * 16 + c) * D_ + g * 8;
#pragma unroll
    for (int ks = 0; ks < 2; ++ks) {
      f32x4 x0 = *(const f32x4*)(qp + ks * 32);
      f32x4 x1 = *(const f32x4*)(qp + ks * 32 + 4);
      bf16x8 t;
      t[0] = f2bf(x0[0]); t[1] = f2bf(x0[1]); t[2] = f2bf(x0[2]); t[3] = f2bf(x0[3]);
      t[4] = f2bf(x1[0]); t[5] = f2bf(x1[1]); t[6] = f2bf(x1[2]); t[7] = f2bf(x1[3]);
      qf[ks] = t;
    }
  }

  const float* Kb = K + (size_t)b * L_ * D_;
  const float* Vb = V + (size_t)b * L_ * D_;
  const int*   Mb = M + (size_t)b * L_ * L_ + (size_t)q0 * L_; // [qrow][key]

  // ---- prefetch registers
  f32x4 kreg[4], vreg[4];
  int4  mreg[4];
  const int vkey4 = (tid & 15) * 4;  // V staging: 4x4 block per thread
  const int vd4   = (tid >> 4) * 4;

  auto stage_load = [&](int t) {
    const float* ksrc = Kb + (size_t)(t * KV) * D_;
    const float* vsrc = Vb + (size_t)(t * KV) * D_;
    const int*   msrc = Mb + t * KV;
#pragma unroll
    for (int i = 0; i < 4; ++i) {
      const int idx = tid + i * 256;   // float4 index in 64x64 tile
      const int row = idx >> 4;        // K: key row; M: q row
      const int d4  = (idx & 15) * 4;
      kreg[i] = *(const f32x4*)(ksrc + (size_t)idx * 4);
      mreg[i] = *(const int4*)(msrc + (size_t)row * L_ + d4);
      vreg[i] = *(const f32x4*)(vsrc + (size_t)(vkey4 + i) * D_ + vd4);
    }
  };

  auto stage_write = [&]() {
#pragma unroll
    for (int i = 0; i < 4; ++i) {
      const int idx = tid + i * 256;
      const int row = idx >> 4;
      const int d4  = (idx & 15) * 4;
      f32x4 kx = kreg[i];
      short4v ks4 = { f2bf(kx[0]), f2bf(kx[1]), f2bf(kx[2]), f2bf(kx[3]) };
      *(short4v*)&k_lds[row][d4] = ks4;
      int4 mm = mreg[i];
      unsigned int packed = (unsigned int)(mm.x != 0)
                          | ((unsigned int)(mm.y != 0) << 8)
                          | ((unsigned int)(mm.z != 0) << 16)
                          | ((unsigned int)(mm.w != 0) << 24);
      *(unsigned int*)&m_lds[row][d4] = packed;
      // V: register 4x4 transpose, one b64 row-chunk write per jj (rotated)
      const int jj = (i + (tid >> 4)) & 3;
      short4v vt4 = { f2bf(vreg[0][jj]), f2bf(vreg[1][jj]),
                      f2bf(vreg[2][jj]), f2bf(vreg[3][jj]) };
      *(short4v*)&vt_lds[vd4 + jj][vkey4] = vt4;
    }
  };

  f32x4 acc[4];
#pragma unroll
  for (int i = 0; i < 4; ++i) acc[i] = (f32x4){0.f, 0.f, 0.f, 0.f};
  float m_run = -INFINITY;  // per-lane, q-row = w*16+c
  float l_run = 0.f;

  stage_load(0);
  stage_write();
  __syncthreads();

  for (int t = 0; t < NKV; ++t) {
    const bool has_next = (t + 1 < NKV);
    if (has_next) stage_load(t + 1);   // latency hides under compute

    // ---- S^T = K Q^T : fragment f covers keys f*16..f*16+15, q-cols 0..15.
    //      C layout: row = key = f*16 + g*4 + r, col = q = c.
    f32x4 sc[4];
#pragma unroll
    for (int f = 0; f < 4; ++f) {
      f32x4 a = (f32x4){0.f, 0.f, 0.f, 0.f};
#pragma unroll
      for (int ks = 0; ks < 2; ++ks) {
        bf16x8 kf = *(const bf16x8*)&k_lds[f * 16 + c][ks * 32 + g * 8];
        a = __builtin_amdgcn_mfma_f32_16x16x32_bf16(kf, qf[ks], a, 0, 0, 0);
      }
      sc[f] = a;
    }

    // ---- scale + mask: lane needs row q=w*16+c, keys f*16+4g+r (contiguous 4B)
    const unsigned char* mrow = &m_lds[w * 16 + c][0];
#pragma unroll
    for (int f = 0; f < 4; ++f) {
      const unsigned int mm4 = *(const unsigned int*)(mrow + f * 16 + 4 * g);
#pragma unroll
      for (int r = 0; r < 4; ++r) {
        sc[f][r] = ((mm4 >> (8 * r)) & 0xffu) ? NEG : sc[f][r] * INV_TEMP;
      }
    }

    // ---- online softmax, per-lane row q=w*16+c (16 in-lane keys x 4 groups)
    float x = -INFINITY;
#pragma unroll
    for (int f = 0; f < 4; ++f)
#pragma unroll
      for (int r = 0; r < 4; ++r) x = fmaxf(x, sc[f][r]);
    x = fmaxf(x, __shfl_xor(x, 16, 64));
    x = fmaxf(x, __shfl_xor(x, 32, 64));
    const float m_new = fmaxf(m_run, x);
    const float alpha = __expf(m_run - m_new);
    float s = 0.f;
#pragma unroll
    for (int f = 0; f < 4; ++f)
#pragma unroll
      for (int r = 0; r < 4; ++r) {
        sc[f][r] = __expf(sc[f][r] - m_new);
        s += sc[f][r];
      }
    s += __shfl_xor(s, 16, 64);
    s += __shfl_xor(s, 32, 64);
    l_run = l_run * alpha + s;
    m_run = m_new;

    // ---- rescale acc: acc rows are q = g*4+r -> fetch alpha from lane c'=g*4+r
    float ar[4];
#pragma unroll
    for (int r = 0; r < 4; ++r)
      ar[r] = __shfl(alpha, (lane & 48) | (g * 4 + r), 64);
#pragma unroll
    for (int fd = 0; fd < 4; ++fd)
#pragma unroll
      for (int r = 0; r < 4; ++r) acc[fd][r] *= ar[r];

    // ---- P -> LDS: lane owns P[q=c][keys f*16+4g+0..3] -> one b64 per f
#pragma unroll
    for (int f = 0; f < 4; ++f) {
      short4v pk = { f2bf(sc[f][0]), f2bf(sc[f][1]), f2bf(sc[f][2]), f2bf(sc[f][3]) };
      *(short4v*)&p_lds[w][c][f * 16 + 4 * g] = pk;
    }

    // ---- O += P V : A=p (row=q=c, k=key), B=V^T (col=d, k=key)
#pragma unroll
    for (int ks = 0; ks < 2; ++ks) {
      bf16x8 pa = *(const bf16x8*)&p_lds[w][c][ks * 32 + g * 8];
#pragma unroll
      for (int fd = 0; fd < 4; ++fd) {
        bf16x8 vb = *(const bf16x8*)&vt_lds[fd * 16 + c][ks * 32 + g * 8];
        acc[fd] = __builtin_amdgcn_mfma_f32_16x16x32_bf16(pa, vb, acc[fd], 0, 0, 0);
      }
    }

    __syncthreads();                  // all waves done reading tile t
    if (has_next) stage_write();      // overwrite LDS with tile t+1
    __syncthreads();                  // tile t+1 visible
  }

  // ---- epilogue: acc[fd][r] = O[q=g*4+r][d=fd*16+c]; l lives at lane c'=q
  const float li = 1.0f / l_run;
  float lr[4];
#pragma unroll
  for (int r = 0; r < 4; ++r)
    lr[r] = __shfl(li, (lane & 48) | (g * 4 + r), 64);
  float* orow = O + ((size_t)b * L_ + q0 + w * 16 + g * 4) * D_;
#pragma unroll
  for (int fd = 0; fd < 4; ++fd)
#pragma unroll
    for (int r = 0; r < 4; ++r)
      orow[(size_t)r * D_ + fd * 16 + c] = acc[fd][r] * lr[r];
}

extern "C" void kernel_launch(void* const* d_in, const int* in_sizes, int n_in,
                              void* d_out, int out_size, void* d_ws, size_t ws_size,
                              hipStream_t stream) {
  const float* q = (const float*)d_in[0];
  const float* k = (const float*)d_in[1];
  const float* v = (const float*)d_in[2];
  const int* m = (const int*)d_in[3]; // jax bool shipped as int32
  float* o = (float*)d_out;
  dim3 grid(L_ / QBLK, B_);
  attn_fwd<<<grid, 256, 0, stream>>>(q, k, v, m, o);
}

// Round 8
// 100.326 us; speedup vs baseline: 1.0859x; 1.0859x over previous
//
#include <hip/hip_runtime.h>
#include <hip/hip_bf16.h>

// Flash-attention fwd, fp32 in/out, bf16 MFMA compute.
// B=64 (batch*heads), L=1024, D=64. scale=1/sqrt(512). mask(int32)!=0 -> -1e9.
// R8: (1) double-buffered K/V LDS, ONE barrier per tile (stage-write targets
//     the idle buffer -> no drain between write and compute); (2) mask read
//     direct global->register in swapped layout (zero reuse => no LDS staging),
//     double-register prefetch one tile ahead (static A/B naming, no scratch);
//     (3) swapped QK^T structure from R7 kept (per-lane softmax rows).

typedef __attribute__((ext_vector_type(4))) float f32x4;
typedef __attribute__((ext_vector_type(8))) short bf16x8;
typedef __attribute__((ext_vector_type(4))) short short4v;

constexpr int B_ = 64;
constexpr int L_ = 1024;
constexpr int D_ = 64;
constexpr int QBLK = 64;     // q rows per block (4 waves x 16)
constexpr int KV = 64;       // keys per tile
constexpr int NKV = L_ / KV; // 16 tiles (even -> clean 2x unroll)
constexpr int STR = 72;      // shorts per LDS row (64 + 8 pad)
constexpr float INV_TEMP = 0.04419417382415922f; // 1/sqrt(512)
constexpr float NEG = -1e9f;

__device__ inline short f2bf(float f) {
  __hip_bfloat16 h = __float2bfloat16(f);
  short s; __builtin_memcpy(&s, &h, 2);
  return s;
}

__global__ __launch_bounds__(256) void attn_fwd(
    const float* __restrict__ Q, const float* __restrict__ K,
    const float* __restrict__ V, const int* __restrict__ M,
    float* __restrict__ O)
{
  __shared__ short k_lds[2][KV][STR];   // K tiles, [buf][key][d]     18.4 KB
  __shared__ short vt_lds[2][D_][STR];  // V^T tiles, [buf][d][key]   18.4 KB
  __shared__ short p_lds[4][16][STR];   // per-wave P, [qrow(c)][key]  9.2 KB

  const int tid  = threadIdx.x;
  const int w    = tid >> 6;
  const int lane = tid & 63;
  const int g    = lane >> 4; // 16-lane group 0..3
  const int c    = lane & 15;
  const int b    = blockIdx.y;
  const int q0   = blockIdx.x * QBLK;

  // ---- Q fragment (B operand of swapped QK^T): col=c -> q-row w*16+c
  bf16x8 qf[2];
  {
    const float* qp = Q + ((size_t)b * L_ + q0 + w * 16 + c) * D_ + g * 8;
#pragma unroll
    for (int ks = 0; ks < 2; ++ks) {
      f32x4 x0 = *(const f32x4*)(qp + ks * 32);
      f32x4 x1 = *(const f32x4*)(qp + ks * 32 + 4);
      bf16x8 t;
      t[0] = f2bf(x0[0]); t[1] = f2bf(x0[1]); t[2] = f2bf(x0[2]); t[3] = f2bf(x0[3]);
      t[4] = f2bf(x1[0]); t[5] = f2bf(x1[1]); t[6] = f2bf(x1[2]); t[7] = f2bf(x1[3]);
      qf[ks] = t;
    }
  }

  const float* Kb = K + (size_t)b * L_ * D_;
  const float* Vb = V + (size_t)b * L_ * D_;
  // mask, swapped layout: lane reads its own row q=w*16+c, keys f*16+4g+0..3
  const int* mlane = M + (size_t)b * L_ * L_ + (size_t)(q0 + w * 16 + c) * L_ + 4 * g;

  f32x4 kreg[4], vreg[4];
  int4  mA[4], mB[4];                 // mask double-register prefetch
  const int vkey4 = (tid & 15) * 4;   // V staging: 4x4 block per thread
  const int vd4   = (tid >> 4) * 4;

  auto load_kv = [&](int t) {
    const float* ksrc = Kb + (size_t)(t * KV) * D_;
    const float* vsrc = Vb + (size_t)(t * KV) * D_;
#pragma unroll
    for (int i = 0; i < 4; ++i) {
      kreg[i] = *(const f32x4*)(ksrc + (size_t)(tid + i * 256) * 4);
      vreg[i] = *(const f32x4*)(vsrc + (size_t)(vkey4 + i) * D_ + vd4);
    }
  };
  auto load_m = [&](int t, int4 (&mr)[4]) {
#pragma unroll
    for (int f = 0; f < 4; ++f) mr[f] = *(const int4*)(mlane + t * KV + f * 16);
  };
  auto write_kv = [&](int buf) {
#pragma unroll
    for (int i = 0; i < 4; ++i) {
      const int idx = tid + i * 256;
      const int row = idx >> 4;
      const int d4  = (idx & 15) * 4;
      f32x4 kx = kreg[i];
      short4v ks4 = { f2bf(kx[0]), f2bf(kx[1]), f2bf(kx[2]), f2bf(kx[3]) };
      *(short4v*)&k_lds[buf][row][d4] = ks4;
      // V: register 4x4 transpose, one b64 row-chunk write (row rotated/group)
      const int jj = (i + (tid >> 4)) & 3;
      short4v vt4 = { f2bf(vreg[0][jj]), f2bf(vreg[1][jj]),
                      f2bf(vreg[2][jj]), f2bf(vreg[3][jj]) };
      *(short4v*)&vt_lds[buf][vd4 + jj][vkey4] = vt4;
    }
  };

  f32x4 acc[4];
#pragma unroll
  for (int i = 0; i < 4; ++i) acc[i] = (f32x4){0.f, 0.f, 0.f, 0.f};
  float m_run = -INFINITY;  // per-lane, q-row = w*16+c
  float l_run = 0.f;

  // prologue: tile 0
  load_kv(0);
  load_m(0, mA);
  write_kv(0);
  __syncthreads();

  auto body = [&](int t, bool has_next, int4 (&mc)[4], int4 (&mn)[4]) {
    const int cur = t & 1;
    if (has_next) { load_kv(t + 1); load_m(t + 1, mn); } // hide under compute

    // ---- S^T = K Q^T : C row = key = f*16+g*4+r, col = q = c
    f32x4 sc[4];
#pragma unroll
    for (int f = 0; f < 4; ++f) {
      f32x4 a = (f32x4){0.f, 0.f, 0.f, 0.f};
#pragma unroll
      for (int ks = 0; ks < 2; ++ks) {
        bf16x8 kf = *(const bf16x8*)&k_lds[cur][f * 16 + c][ks * 32 + g * 8];
        a = __builtin_amdgcn_mfma_f32_16x16x32_bf16(kf, qf[ks], a, 0, 0, 0);
      }
      sc[f] = a;
    }

    // ---- scale + mask from registers (lane's own row, keys f*16+4g+r)
#pragma unroll
    for (int f = 0; f < 4; ++f) {
      const int4 mm = mc[f];
      sc[f][0] = mm.x ? NEG : sc[f][0] * INV_TEMP;
      sc[f][1] = mm.y ? NEG : sc[f][1] * INV_TEMP;
      sc[f][2] = mm.z ? NEG : sc[f][2] * INV_TEMP;
      sc[f][3] = mm.w ? NEG : sc[f][3] * INV_TEMP;
    }

    // ---- online softmax, per-lane row (16 in-lane keys x 4 lane-groups)
    float x = -INFINITY;
#pragma unroll
    for (int f = 0; f < 4; ++f)
#pragma unroll
      for (int r = 0; r < 4; ++r) x = fmaxf(x, sc[f][r]);
    x = fmaxf(x, __shfl_xor(x, 16, 64));
    x = fmaxf(x, __shfl_xor(x, 32, 64));
    const float m_new = fmaxf(m_run, x);
    const float alpha = __expf(m_run - m_new);
    float s = 0.f;
#pragma unroll
    for (int f = 0; f < 4; ++f)
#pragma unroll
      for (int r = 0; r < 4; ++r) {
        sc[f][r] = __expf(sc[f][r] - m_new);
        s += sc[f][r];
      }
    s += __shfl_xor(s, 16, 64);
    s += __shfl_xor(s, 32, 64);
    l_run = l_run * alpha + s;
    m_run = m_new;

    // ---- rescale acc: acc rows are q=g*4+r -> alpha from lane c'=g*4+r
    float ar[4];
#pragma unroll
    for (int r = 0; r < 4; ++r)
      ar[r] = __shfl(alpha, (lane & 48) | (g * 4 + r), 64);
#pragma unroll
    for (int fd = 0; fd < 4; ++fd)
#pragma unroll
      for (int r = 0; r < 4; ++r) acc[fd][r] *= ar[r];

    // ---- P -> LDS: lane owns P[q=c][keys f*16+4g+0..3] -> one b64 per f
#pragma unroll
    for (int f = 0; f < 4; ++f) {
      short4v pk = { f2bf(sc[f][0]), f2bf(sc[f][1]), f2bf(sc[f][2]), f2bf(sc[f][3]) };
      *(short4v*)&p_lds[w][c][f * 16 + 4 * g] = pk;
    }

    // ---- O += P V
#pragma unroll
    for (int ks = 0; ks < 2; ++ks) {
      bf16x8 pa = *(const bf16x8*)&p_lds[w][c][ks * 32 + g * 8];
#pragma unroll
      for (int fd = 0; fd < 4; ++fd) {
        bf16x8 vb = *(const bf16x8*)&vt_lds[cur][fd * 16 + c][ks * 32 + g * 8];
        acc[fd] = __builtin_amdgcn_mfma_f32_16x16x32_bf16(pa, vb, acc[fd], 0, 0, 0);
      }
    }

    // stage next tile into the idle buffer; ONE barrier flips it
    if (has_next) write_kv(cur ^ 1);
    __syncthreads();
  };

  for (int tt = 0; tt < NKV; tt += 2) {
    body(tt,     true,          mA, mB);   // tt <= 14 -> tt+1 always valid
    body(tt + 1, tt + 2 < NKV,  mB, mA);
  }

  // ---- epilogue: acc[fd][r] = O[q=g*4+r][d=fd*16+c]; l lives at lane c'=q
  const float li = 1.0f / l_run;
  float lr[4];
#pragma unroll
  for (int r = 0; r < 4; ++r)
    lr[r] = __shfl(li, (lane & 48) | (g * 4 + r), 64);
  float* orow = O + ((size_t)b * L_ + q0 + w * 16 + g * 4) * D_;
#pragma unroll
  for (int fd = 0; fd < 4; ++fd)
#pragma unroll
    for (int r = 0; r < 4; ++r)
      orow[(size_t)r * D_ + fd * 16 + c] = acc[fd][r] * lr[r];
}

extern "C" void kernel_launch(void* const* d_in, const int* in_sizes, int n_in,
                              void* d_out, int out_size, void* d_ws, size_t ws_size,
                              hipStream_t stream) {
  const float* q = (const float*)d_in[0];
  const float* k = (const float*)d_in[1];
  const float* v = (const float*)d_in[2];
  const int* m = (const int*)d_in[3]; // jax bool shipped as int32
  float* o = (float*)d_out;
  dim3 grid(L_ / QBLK, B_);
  attn_fwd<<<grid, 256, 0, stream>>>(q, k, v, m, o);
}